// Round 2
// baseline (1996.051 us; speedup 1.0000x reference)
//
#include <hip/hip_runtime.h>

// ---------------- problem constants ----------------
#define B_  2
#define T_  2048
#define H_  2048
#define A_  2048
#define F_  8192
#define BT_ 4096   // B*T rows

typedef __bf16  bf16x8 __attribute__((ext_vector_type(8)));
typedef float   f32x4  __attribute__((ext_vector_type(4)));
typedef short   short8 __attribute__((ext_vector_type(8)));

__device__ __forceinline__ float bf2f(unsigned short b) {
  return __uint_as_float(((unsigned)b) << 16);
}
__device__ __forceinline__ unsigned short f2bf(float f) {
  unsigned u = __float_as_uint(f);
  unsigned r = (u + 0x7FFFu + ((u >> 16) & 1u)) >> 16;   // RNE
  return (unsigned short)r;
}

// global -> LDS direct copy, 16B per lane
typedef __attribute__((address_space(3))) void lds_void_t;
typedef __attribute__((address_space(1))) const void gc_void_t;
__device__ __forceinline__ void gload_lds16(const void* g, void* l) {
  __builtin_amdgcn_global_load_lds((gc_void_t*)g, (lds_void_t*)l, 16, 0, 0);
}

// ---------------- canary: ws too small diagnostic ----------------
__global__ void canary_kernel(float* out) { out[threadIdx.x] = 1000.0f; }

// ---------------- weight transpose + fp32->bf16 ----------------
// src [Kd][Nd] fp32 row-major  ->  dst [Nd][Kd] bf16 row-major
__global__ __launch_bounds__(256) void transpose_bf16_kernel(
    const float* __restrict__ src, unsigned short* __restrict__ dst, int Kd, int Nd)
{
  __shared__ float tile[32][33];
  const int tx = threadIdx.x & 31;
  const int ty = threadIdx.x >> 5;         // 0..7
  const int n0 = blockIdx.x * 32;
  const int k0 = blockIdx.y * 32;
#pragma unroll
  for (int i = 0; i < 32; i += 8)
    tile[ty + i][tx] = src[(size_t)(k0 + ty + i) * Nd + n0 + tx];
  __syncthreads();
#pragma unroll
  for (int i = 0; i < 32; i += 8)
    dst[(size_t)(n0 + ty + i) * Kd + k0 + tx] = f2bf(tile[tx][ty + i]);
}

// ---------------- block reduction (sum, sumsq) ----------------
__device__ __forceinline__ void block_reduce2(float& a, float& b) {
#pragma unroll
  for (int off = 32; off > 0; off >>= 1) {
    a += __shfl_down(a, off, 64);
    b += __shfl_down(b, off, 64);
  }
  __shared__ float sa[4], sb[4];
  const int lane = threadIdx.x & 63, w = threadIdx.x >> 6;
  __syncthreads();
  if (lane == 0) { sa[w] = a; sb[w] = b; }
  __syncthreads();
  a = sa[0] + sa[1] + sa[2] + sa[3];
  b = sb[0] + sb[1] + sb[2] + sb[3];
}

// ---------------- pre-LN + LN1 fused ----------------
// h0 = LN(hidden; pre)  -> fp32 (d_out, residual base)
// x1 = LN(h0; ln1)      -> bf16
__global__ __launch_bounds__(256) void ln_pre_kernel(
    const float* __restrict__ hidden,
    const float* __restrict__ pw, const float* __restrict__ pb,
    const float* __restrict__ w1, const float* __restrict__ b1,
    float* __restrict__ h0, unsigned short* __restrict__ x1)
{
  const int row = blockIdx.x, tid = threadIdx.x;
  const int c0 = tid * 8;
  const size_t base = (size_t)row * H_ + c0;
  float x[8];
  float4 v0 = *(const float4*)(hidden + base);
  float4 v1 = *(const float4*)(hidden + base + 4);
  x[0]=v0.x; x[1]=v0.y; x[2]=v0.z; x[3]=v0.w;
  x[4]=v1.x; x[5]=v1.y; x[6]=v1.z; x[7]=v1.w;
  float s = 0.f, s2 = 0.f;
#pragma unroll
  for (int j = 0; j < 8; ++j) { s += x[j]; s2 += x[j]*x[j]; }
  block_reduce2(s, s2);
  float mu  = s * (1.f / H_);
  float inv = rsqrtf(fmaxf(s2 * (1.f / H_) - mu*mu, 0.f) + 1e-5f);
  float y[8];
#pragma unroll
  for (int j = 0; j < 8; ++j) y[j] = (x[j] - mu) * inv * pw[c0+j] + pb[c0+j];
  *(float4*)(h0 + base)     = make_float4(y[0],y[1],y[2],y[3]);
  *(float4*)(h0 + base + 4) = make_float4(y[4],y[5],y[6],y[7]);
  s = 0.f; s2 = 0.f;
#pragma unroll
  for (int j = 0; j < 8; ++j) { s += y[j]; s2 += y[j]*y[j]; }
  block_reduce2(s, s2);
  mu  = s * (1.f / H_);
  inv = rsqrtf(fmaxf(s2 * (1.f / H_) - mu*mu, 0.f) + 1e-5f);
  unsigned o[4];
#pragma unroll
  for (int p = 0; p < 4; ++p) {
    unsigned lo = f2bf((y[2*p]   - mu) * inv * w1[c0+2*p]   + b1[c0+2*p]);
    unsigned hi = f2bf((y[2*p+1] - mu) * inv * w1[c0+2*p+1] + b1[c0+2*p+1]);
    o[p] = lo | (hi << 16);
  }
  *(uint4*)(x1 + base) = make_uint4(o[0], o[1], o[2], o[3]);
}

// ---------------- single LN (fp32 in) -> bf16 ----------------
__global__ __launch_bounds__(256) void ln_single_kernel(
    const float* __restrict__ in, const float* __restrict__ w_, const float* __restrict__ b_,
    unsigned short* __restrict__ outb)
{
  const int row = blockIdx.x, tid = threadIdx.x;
  const int c0 = tid * 8;
  const size_t base = (size_t)row * H_ + c0;
  float x[8];
  float4 v0 = *(const float4*)(in + base);
  float4 v1 = *(const float4*)(in + base + 4);
  x[0]=v0.x; x[1]=v0.y; x[2]=v0.z; x[3]=v0.w;
  x[4]=v1.x; x[5]=v1.y; x[6]=v1.z; x[7]=v1.w;
  float s = 0.f, s2 = 0.f;
#pragma unroll
  for (int j = 0; j < 8; ++j) { s += x[j]; s2 += x[j]*x[j]; }
  block_reduce2(s, s2);
  float mu  = s * (1.f / H_);
  float inv = rsqrtf(fmaxf(s2 * (1.f / H_) - mu*mu, 0.f) + 1e-5f);
  unsigned o[4];
#pragma unroll
  for (int p = 0; p < 4; ++p) {
    unsigned lo = f2bf((x[2*p]   - mu) * inv * w_[c0+2*p]   + b_[c0+2*p]);
    unsigned hi = f2bf((x[2*p+1] - mu) * inv * w_[c0+2*p+1] + b_[c0+2*p+1]);
    o[p] = lo | (hi << 16);
  }
  *(uint4*)(outb + base) = make_uint4(o[0], o[1], o[2], o[3]);
}

// ---------------- token-shift + mix (single output) ----------------
// out = c + (x - c) * tm,  c = (t>0 ? x[row-1] : 0)
__global__ __launch_bounds__(256) void mix1_kernel(
    const unsigned short* __restrict__ x,
    const float* __restrict__ tm_,
    unsigned short* __restrict__ outb)
{
  const int row = blockIdx.x;
  const int t = row & (T_ - 1);
  const int c0 = threadIdx.x * 8;
  const size_t base = (size_t)row * H_ + c0;
  uint4 xv = *(const uint4*)(x + base);
  uint4 cv = make_uint4(0u,0u,0u,0u);
  if (t > 0) cv = *(const uint4*)(x + base - H_);
  const unsigned xs[4] = {xv.x, xv.y, xv.z, xv.w};
  const unsigned cs[4] = {cv.x, cv.y, cv.z, cv.w};
  unsigned oo[4];
#pragma unroll
  for (int p = 0; p < 4; ++p) {
    unsigned w = 0;
#pragma unroll
    for (int h = 0; h < 2; ++h) {
      const int j = p*2 + h;
      float xf = bf2f((unsigned short)((xs[p] >> (h*16)) & 0xFFFFu));
      float cf = bf2f((unsigned short)((cs[p] >> (h*16)) & 0xFFFFu));
      w |= (unsigned)f2bf(fmaf(xf - cf, tm_[c0+j], cf)) << (h*16);
    }
    oo[p] = w;
  }
  *(uint4*)(outb + base) = make_uint4(oo[0],oo[1],oo[2],oo[3]);
}

// ---------------- serial WKV scan (bf16 in/out), 8-deep prefetch ----------------
__global__ __launch_bounds__(256) void wkv_kernel(
    const unsigned short* __restrict__ kg, const unsigned short* __restrict__ vg,
    const unsigned short* __restrict__ rg,
    const float* __restrict__ time_first, const float* __restrict__ time_decay,
    unsigned short* __restrict__ rwkv)
{
  const int g = blockIdx.x * 256 + threadIdx.x;  // 0..4095
  const int b = g >> 11;
  const int a = g & (A_ - 1);
  const float tf = time_first[a];
  const float w  = -__expf(time_decay[a]);
  const size_t base = (size_t)b * T_ * A_ + a;
  float kb[8], vb[8], rb[8];
#pragma unroll
  for (int j = 0; j < 8; ++j) {
    const size_t ix = base + (size_t)j * A_;
    kb[j] = bf2f(kg[ix]); vb[j] = bf2f(vg[ix]); rb[j] = bf2f(rg[ix]);
  }
  float aa = 0.f, bb = 0.f, pp = -1e38f;
  for (int t0 = 0; t0 < T_; t0 += 8) {
#pragma unroll
    for (int j = 0; j < 8; ++j) {
      const int t = t0 + j;
      const float kk = kb[j], vv = vb[j], rr = rb[j];
      const int tn = t + 8;
      if (tn < T_) {                       // refill slot 8 iters ahead
        const size_t ix = base + (size_t)tn * A_;
        kb[j] = bf2f(kg[ix]); vb[j] = bf2f(vg[ix]); rb[j] = bf2f(rg[ix]);
      }
      float ww = tf + kk;
      float q  = fmaxf(pp, ww);
      float e1 = __expf(pp - q);
      float e2 = __expf(ww - q);
      float out = (e1*aa + e2*vv) / (e1*bb + e2);
      float sr  = 1.f / (1.f + __expf(-rr));
      rwkv[base + (size_t)t * A_] = f2bf(sr * out);
      float ww2 = w + pp;
      float q2  = fmaxf(ww2, kk);
      e1 = __expf(ww2 - q2);
      e2 = __expf(kk  - q2);
      aa = e1*aa + e2*vv;
      bb = e1*bb + e2;
      pp = q2;
    }
  }
}

// ---------------- bf16 GEMM, m97 structure ----------------
// A [M,K] bf16 row-major, Bt [N,K] bf16 row-major, tile 128x128, BK=32.
// 4 waves (2x2), each 64x64 = 4x4 fragments of 16x16x32 MFMA.
enum { EPI_BF16 = 0, EPI_ADDIP = 1, EPI_RELU2 = 2, EPI_SIGADD = 3 };

template <int EPI>
__global__ __launch_bounds__(256) void gemm_bt_kernel(
    const unsigned short* __restrict__ Ap, const unsigned short* __restrict__ Bp,
    void* __restrict__ Cp, int K, int N,
    const unsigned short* __restrict__ sigb)
{
  __shared__ unsigned short As[128 * 32];
  __shared__ unsigned short Bs[128 * 32];
  const int tid  = threadIdx.x;
  const int lane = tid & 63;
  const int wv   = tid >> 6;
  const int wr   = wv >> 1, wc = wv & 1;
  const long row0 = (long)blockIdx.y * 128;
  const long col0 = (long)blockIdx.x * 128;
  const unsigned short* Ab = Ap + (size_t)row0 * K;
  const unsigned short* Bb = Bp + (size_t)col0 * K;
  const int srow = tid >> 2;          // 0..63
  const int scol = (tid & 3) << 3;    // 0,8,16,24
  const int lr = lane & 15;
  const int hi = lane >> 4;
  f32x4 acc[4][4] = {};
  for (int kt = 0; kt < K; kt += 32) {
    gload_lds16(Ab + (size_t)srow        * K + kt + scol, As + tid * 8);
    gload_lds16(Ab + (size_t)(srow + 64) * K + kt + scol, As + 2048 + tid * 8);
    gload_lds16(Bb + (size_t)srow        * K + kt + scol, Bs + tid * 8);
    gload_lds16(Bb + (size_t)(srow + 64) * K + kt + scol, Bs + 2048 + tid * 8);
    __syncthreads();
    bf16x8 af[4], bfr[4];
#pragma unroll
    for (int m = 0; m < 4; ++m)
      af[m] = __builtin_bit_cast(bf16x8,
          *(const short8*)(As + (wr*64 + m*16 + lr) * 32 + hi * 8));
#pragma unroll
    for (int n = 0; n < 4; ++n)
      bfr[n] = __builtin_bit_cast(bf16x8,
          *(const short8*)(Bs + (wc*64 + n*16 + lr) * 32 + hi * 8));
#pragma unroll
    for (int m = 0; m < 4; ++m)
#pragma unroll
      for (int n = 0; n < 4; ++n)
        acc[m][n] = __builtin_amdgcn_mfma_f32_16x16x32_bf16(af[m], bfr[n], acc[m][n], 0, 0, 0);
    __syncthreads();
  }
  // C/D layout: col = lane&15, row = (lane>>4)*4 + j
#pragma unroll
  for (int m = 0; m < 4; ++m) {
#pragma unroll
    for (int n = 0; n < 4; ++n) {
      const long col = col0 + wc*64 + n*16 + lr;
#pragma unroll
      for (int j = 0; j < 4; ++j) {
        const long row = row0 + wr*64 + m*16 + hi*4 + j;
        const size_t idx = (size_t)row * N + col;
        const float v = acc[m][n][j];
        if (EPI == EPI_BF16) {
          ((unsigned short*)Cp)[idx] = f2bf(v);
        } else if (EPI == EPI_ADDIP) {
          float* C = (float*)Cp;
          C[idx] = C[idx] + v;                       // in-place residual add
        } else if (EPI == EPI_RELU2) {
          float rr = v > 0.f ? v : 0.f;
          ((unsigned short*)Cp)[idx] = f2bf(rr * rr);
        } else {                                     // EPI_SIGADD
          float s = 1.f / (1.f + __expf(-bf2f(sigb[idx])));
          float* C = (float*)Cp;
          C[idx] = C[idx] + s * v;
        }
      }
    }
  }
}

// ---------------- workspace layout ----------------
#define MB(x) ((size_t)(x) << 20)
// weights (bf16, transposed [N][K]):
//   WkT 0..8, WvT 8..16, WrT 16..24, WoT 24..32, fWrT 32..40,
//   fWkT 40..72, fWvT 72..104
// activations:
//   S1 104..120 (x1 -> rwkv), S4 120..136 (r)          [KK strip aliases 104..136]
//   S2 136..152 (k -> x2),   S3 152..168 (v -> r2pre)
//   M1 168..184 (mix buffer: kx/vx/rx/rx2/kx2)
#define WS_NEED MB(184)

extern "C" void kernel_launch(void* const* d_in, const int* in_sizes, int n_in,
                              void* d_out, int out_size, void* d_ws, size_t ws_size,
                              hipStream_t stream) {
  const float* hidden     = (const float*)d_in[0];
  const float* pre_w      = (const float*)d_in[1];
  const float* pre_b      = (const float*)d_in[2];
  const float* ln1_w      = (const float*)d_in[3];
  const float* ln1_b      = (const float*)d_in[4];
  const float* ln2_w      = (const float*)d_in[5];
  const float* ln2_b      = (const float*)d_in[6];
  const float* time_decay = (const float*)d_in[7];
  const float* time_first = (const float*)d_in[8];
  const float* tmk        = (const float*)d_in[9];
  const float* tmv        = (const float*)d_in[10];
  const float* tmr        = (const float*)d_in[11];
  const float* Wk         = (const float*)d_in[12];
  const float* Wv         = (const float*)d_in[13];
  const float* Wr         = (const float*)d_in[14];
  const float* Wo         = (const float*)d_in[15];
  const float* f_tmk      = (const float*)d_in[16];
  const float* f_tmr      = (const float*)d_in[17];
  const float* f_Wk       = (const float*)d_in[18];
  const float* f_Wr       = (const float*)d_in[19];
  const float* f_Wv       = (const float*)d_in[20];
  float* out = (float*)d_out;
  char*  ws  = (char*)d_ws;

  if (ws_size < WS_NEED) {               // diagnostic canary: absmax ~1000 => ws too small
    canary_kernel<<<1, 256, 0, stream>>>(out);
    return;
  }

  unsigned short* WkT  = (unsigned short*)(ws + MB(0));
  unsigned short* WvT  = (unsigned short*)(ws + MB(8));
  unsigned short* WrT  = (unsigned short*)(ws + MB(16));
  unsigned short* WoT  = (unsigned short*)(ws + MB(24));
  unsigned short* fWrT = (unsigned short*)(ws + MB(32));
  unsigned short* fWkT = (unsigned short*)(ws + MB(40));
  unsigned short* fWvT = (unsigned short*)(ws + MB(72));
  unsigned short* S1   = (unsigned short*)(ws + MB(104));  // x1 -> rwkv
  unsigned short* KK   = (unsigned short*)(ws + MB(104));  // kk2 strip [2048,8192] (aliases S1+S4)
  unsigned short* S4   = (unsigned short*)(ws + MB(120));  // r
  unsigned short* S2   = (unsigned short*)(ws + MB(136));  // k -> x2
  unsigned short* S3   = (unsigned short*)(ws + MB(152));  // v -> r2pre
  unsigned short* M1   = (unsigned short*)(ws + MB(168));  // mix scratch

  const dim3 blk(256);

  // 1) weight transpose+convert: src [Kd,Nd] fp32 -> dst [Nd,Kd] bf16
  transpose_bf16_kernel<<<dim3(64, 64),  blk, 0, stream>>>(Wk,   WkT,  2048, 2048);
  transpose_bf16_kernel<<<dim3(64, 64),  blk, 0, stream>>>(Wv,   WvT,  2048, 2048);
  transpose_bf16_kernel<<<dim3(64, 64),  blk, 0, stream>>>(Wr,   WrT,  2048, 2048);
  transpose_bf16_kernel<<<dim3(64, 64),  blk, 0, stream>>>(Wo,   WoT,  2048, 2048);
  transpose_bf16_kernel<<<dim3(64, 64),  blk, 0, stream>>>(f_Wr, fWrT, 2048, 2048);
  transpose_bf16_kernel<<<dim3(256, 64), blk, 0, stream>>>(f_Wk, fWkT, 2048, 8192);
  transpose_bf16_kernel<<<dim3(64, 256), blk, 0, stream>>>(f_Wv, fWvT, 8192, 2048);

  // 2) pre-LN + LN1: h0 -> d_out (fp32), x1 -> S1 (bf16)
  ln_pre_kernel<<<BT_, blk, 0, stream>>>(hidden, pre_w, pre_b, ln1_w, ln1_b, out, S1);

  // 3) k/v/r projections via shared mix buffer M1
  mix1_kernel<<<BT_, blk, 0, stream>>>(S1, tmk, M1);
  gemm_bt_kernel<EPI_BF16><<<dim3(16, 32), blk, 0, stream>>>(M1, WkT, S2, 2048, 2048, nullptr);
  mix1_kernel<<<BT_, blk, 0, stream>>>(S1, tmv, M1);
  gemm_bt_kernel<EPI_BF16><<<dim3(16, 32), blk, 0, stream>>>(M1, WvT, S3, 2048, 2048, nullptr);
  mix1_kernel<<<BT_, blk, 0, stream>>>(S1, tmr, M1);
  gemm_bt_kernel<EPI_BF16><<<dim3(16, 32), blk, 0, stream>>>(M1, WrT, S4, 2048, 2048, nullptr);

  // 4) serial WKV scan + sigmoid(r)*wkv -> S1 (x1 dead)
  wkv_kernel<<<dim3(16), blk, 0, stream>>>(S2, S3, S4, time_first, time_decay, S1);

  // 5) h1 = h0 + rwkv @ Wo  (in-place on d_out)
  gemm_bt_kernel<EPI_ADDIP><<<dim3(16, 32), blk, 0, stream>>>(S1, WoT, out, 2048, 2048, nullptr);

  // 6) LN2: d_out -> x2 (S2, k dead)
  ln_single_kernel<<<BT_, blk, 0, stream>>>(out, ln2_w, ln2_b, S2);

  // 7) r2pre = rx2 @ f_Wr -> S3 (v dead)
  mix1_kernel<<<BT_, blk, 0, stream>>>(S2, f_tmr, M1);
  gemm_bt_kernel<EPI_BF16><<<dim3(16, 32), blk, 0, stream>>>(M1, fWrT, S3, 2048, 2048, nullptr);

  // 8) kx2 -> M1 (stays live for both strips)
  mix1_kernel<<<BT_, blk, 0, stream>>>(S2, f_tmk, M1);

  // 9) FF in 2 strips of 2048 rows: kk2 = relu(kx2@f_Wk)^2 -> KK;
  //    out += sigmoid(r2pre) * (kk2 @ f_Wv)  (in-place on d_out)
  for (int s = 0; s < 2; ++s) {
    const size_t rowoff = (size_t)s * 2048;
    gemm_bt_kernel<EPI_RELU2><<<dim3(64, 16), blk, 0, stream>>>(
        M1 + rowoff * 2048, fWkT, KK, 2048, 8192, nullptr);
    gemm_bt_kernel<EPI_SIGADD><<<dim3(16, 16), blk, 0, stream>>>(
        KK, fWvT, out + rowoff * 2048, 8192, 2048, S3 + rowoff * 2048);
  }
}

// Round 3
// 1098.140 us; speedup vs baseline: 1.8177x; 1.8177x over previous
//
#include <hip/hip_runtime.h>

// ---------------- problem constants ----------------
#define B_  2
#define T_  2048
#define H_  2048
#define A_  2048
#define F_  8192
#define BT_ 4096   // B*T rows

typedef __bf16  bf16x8 __attribute__((ext_vector_type(8)));
typedef float   f32x4  __attribute__((ext_vector_type(4)));
typedef short   short8 __attribute__((ext_vector_type(8)));

__device__ __forceinline__ float bf2f(unsigned short b) {
  return __uint_as_float(((unsigned)b) << 16);
}
__device__ __forceinline__ unsigned short f2bf(float f) {
  unsigned u = __float_as_uint(f);
  unsigned r = (u + 0x7FFFu + ((u >> 16) & 1u)) >> 16;   // RNE
  return (unsigned short)r;
}

// global -> LDS direct copy, 16B per lane
typedef __attribute__((address_space(3))) void lds_void_t;
typedef __attribute__((address_space(1))) const void gc_void_t;
__device__ __forceinline__ void gload_lds16(const void* g, void* l) {
  __builtin_amdgcn_global_load_lds((gc_void_t*)g, (lds_void_t*)l, 16, 0, 0);
}

// ---------------- canary: ws too small diagnostic ----------------
__global__ void canary_kernel(float* out) { out[threadIdx.x] = 1000.0f; }

// ---------------- weight transpose + fp32->bf16 ----------------
// src [Kd][Nd] fp32 row-major  ->  dst [Nd][Kd] bf16 row-major
__global__ __launch_bounds__(256) void transpose_bf16_kernel(
    const float* __restrict__ src, unsigned short* __restrict__ dst, int Kd, int Nd)
{
  __shared__ float tile[32][33];
  const int tx = threadIdx.x & 31;
  const int ty = threadIdx.x >> 5;         // 0..7
  const int n0 = blockIdx.x * 32;
  const int k0 = blockIdx.y * 32;
#pragma unroll
  for (int i = 0; i < 32; i += 8)
    tile[ty + i][tx] = src[(size_t)(k0 + ty + i) * Nd + n0 + tx];
  __syncthreads();
#pragma unroll
  for (int i = 0; i < 32; i += 8)
    dst[(size_t)(n0 + ty + i) * Kd + k0 + tx] = f2bf(tile[tx][ty + i]);
}

// ---------------- block reduction (sum, sumsq) ----------------
__device__ __forceinline__ void block_reduce2(float& a, float& b) {
#pragma unroll
  for (int off = 32; off > 0; off >>= 1) {
    a += __shfl_down(a, off, 64);
    b += __shfl_down(b, off, 64);
  }
  __shared__ float sa[4], sb[4];
  const int lane = threadIdx.x & 63, w = threadIdx.x >> 6;
  __syncthreads();
  if (lane == 0) { sa[w] = a; sb[w] = b; }
  __syncthreads();
  a = sa[0] + sa[1] + sa[2] + sa[3];
  b = sb[0] + sb[1] + sb[2] + sb[3];
}

// ---------------- pre-LN + LN1 fused ----------------
__global__ __launch_bounds__(256) void ln_pre_kernel(
    const float* __restrict__ hidden,
    const float* __restrict__ pw, const float* __restrict__ pb,
    const float* __restrict__ w1, const float* __restrict__ b1,
    float* __restrict__ h0, unsigned short* __restrict__ x1)
{
  const int row = blockIdx.x, tid = threadIdx.x;
  const int c0 = tid * 8;
  const size_t base = (size_t)row * H_ + c0;
  float x[8];
  float4 v0 = *(const float4*)(hidden + base);
  float4 v1 = *(const float4*)(hidden + base + 4);
  x[0]=v0.x; x[1]=v0.y; x[2]=v0.z; x[3]=v0.w;
  x[4]=v1.x; x[5]=v1.y; x[6]=v1.z; x[7]=v1.w;
  float s = 0.f, s2 = 0.f;
#pragma unroll
  for (int j = 0; j < 8; ++j) { s += x[j]; s2 += x[j]*x[j]; }
  block_reduce2(s, s2);
  float mu  = s * (1.f / H_);
  float inv = rsqrtf(fmaxf(s2 * (1.f / H_) - mu*mu, 0.f) + 1e-5f);
  float y[8];
#pragma unroll
  for (int j = 0; j < 8; ++j) y[j] = (x[j] - mu) * inv * pw[c0+j] + pb[c0+j];
  *(float4*)(h0 + base)     = make_float4(y[0],y[1],y[2],y[3]);
  *(float4*)(h0 + base + 4) = make_float4(y[4],y[5],y[6],y[7]);
  s = 0.f; s2 = 0.f;
#pragma unroll
  for (int j = 0; j < 8; ++j) { s += y[j]; s2 += y[j]*y[j]; }
  block_reduce2(s, s2);
  mu  = s * (1.f / H_);
  inv = rsqrtf(fmaxf(s2 * (1.f / H_) - mu*mu, 0.f) + 1e-5f);
  unsigned o[4];
#pragma unroll
  for (int p = 0; p < 4; ++p) {
    unsigned lo = f2bf((y[2*p]   - mu) * inv * w1[c0+2*p]   + b1[c0+2*p]);
    unsigned hi = f2bf((y[2*p+1] - mu) * inv * w1[c0+2*p+1] + b1[c0+2*p+1]);
    o[p] = lo | (hi << 16);
  }
  *(uint4*)(x1 + base) = make_uint4(o[0], o[1], o[2], o[3]);
}

// ---------------- single LN (fp32 in) -> bf16 ----------------
__global__ __launch_bounds__(256) void ln_single_kernel(
    const float* __restrict__ in, const float* __restrict__ w_, const float* __restrict__ b_,
    unsigned short* __restrict__ outb)
{
  const int row = blockIdx.x, tid = threadIdx.x;
  const int c0 = tid * 8;
  const size_t base = (size_t)row * H_ + c0;
  float x[8];
  float4 v0 = *(const float4*)(in + base);
  float4 v1 = *(const float4*)(in + base + 4);
  x[0]=v0.x; x[1]=v0.y; x[2]=v0.z; x[3]=v0.w;
  x[4]=v1.x; x[5]=v1.y; x[6]=v1.z; x[7]=v1.w;
  float s = 0.f, s2 = 0.f;
#pragma unroll
  for (int j = 0; j < 8; ++j) { s += x[j]; s2 += x[j]*x[j]; }
  block_reduce2(s, s2);
  float mu  = s * (1.f / H_);
  float inv = rsqrtf(fmaxf(s2 * (1.f / H_) - mu*mu, 0.f) + 1e-5f);
  unsigned o[4];
#pragma unroll
  for (int p = 0; p < 4; ++p) {
    unsigned lo = f2bf((x[2*p]   - mu) * inv * w_[c0+2*p]   + b_[c0+2*p]);
    unsigned hi = f2bf((x[2*p+1] - mu) * inv * w_[c0+2*p+1] + b_[c0+2*p+1]);
    o[p] = lo | (hi << 16);
  }
  *(uint4*)(outb + base) = make_uint4(o[0], o[1], o[2], o[3]);
}

// ---------------- token-shift + mix (single output) ----------------
__global__ __launch_bounds__(256) void mix1_kernel(
    const unsigned short* __restrict__ x,
    const float* __restrict__ tm_,
    unsigned short* __restrict__ outb)
{
  const int row = blockIdx.x;
  const int t = row & (T_ - 1);
  const int c0 = threadIdx.x * 8;
  const size_t base = (size_t)row * H_ + c0;
  uint4 xv = *(const uint4*)(x + base);
  uint4 cv = make_uint4(0u,0u,0u,0u);
  if (t > 0) cv = *(const uint4*)(x + base - H_);
  const unsigned xs[4] = {xv.x, xv.y, xv.z, xv.w};
  const unsigned cs[4] = {cv.x, cv.y, cv.z, cv.w};
  unsigned oo[4];
#pragma unroll
  for (int p = 0; p < 4; ++p) {
    unsigned w = 0;
#pragma unroll
    for (int h = 0; h < 2; ++h) {
      const int j = p*2 + h;
      float xf = bf2f((unsigned short)((xs[p] >> (h*16)) & 0xFFFFu));
      float cf = bf2f((unsigned short)((cs[p] >> (h*16)) & 0xFFFFu));
      w |= (unsigned)f2bf(fmaf(xf - cf, tm_[c0+j], cf)) << (h*16);
    }
    oo[p] = w;
  }
  *(uint4*)(outb + base) = make_uint4(oo[0],oo[1],oo[2],oo[3]);
}

// ---------------- chunked-parallel WKV scan ----------------
// Associativity: with a-hat = aa*e^pp, the recurrence is a-hat_t = e^w * a-hat_{t-1} + e^{k_t} v_t
// (same for b-hat). Chunk T into C chunks of L; pass 1 computes per-chunk local summaries from
// zero state; LDS combine produces each chunk's incoming prefix; pass 2 replays chunks with the
// true prefix using the exact original per-step code.
#define WKV_G 32   // channels per block
#define WKV_C 32   // chunks over T
#define WKV_L 64   // steps per chunk (WKV_C*WKV_L == T_)

__global__ __launch_bounds__(1024) void wkv_scan_kernel(
    const unsigned short* __restrict__ kg, const unsigned short* __restrict__ vg,
    const unsigned short* __restrict__ rg,
    const float* __restrict__ time_first, const float* __restrict__ time_decay,
    unsigned short* __restrict__ rwkv)
{
  const int tid = threadIdx.x;
  const int al  = tid & (WKV_G - 1);        // channel within group
  const int c   = tid >> 5;                 // chunk index 0..31
  const int b   = blockIdx.x >> 6;          // 64 groups per batch
  const int ag  = blockIdx.x & 63;
  const int a   = ag * WKV_G + al;
  const float tf = time_first[a];
  const float w  = -__expf(time_decay[a]);
  const size_t cb = (size_t)b * T_ * A_ + a + (size_t)c * WKV_L * A_;

  // ---- pass 1: per-chunk summary from zero state (k,v only) ----
  float aa = 0.f, bb = 0.f, pp = -1e38f;
  {
    float kb[4], vb[4];
#pragma unroll
    for (int j = 0; j < 4; ++j) {
      kb[j] = bf2f(kg[cb + (size_t)j * A_]);
      vb[j] = bf2f(vg[cb + (size_t)j * A_]);
    }
    for (int t0 = 0; t0 < WKV_L; t0 += 4) {
#pragma unroll
      for (int j = 0; j < 4; ++j) {
        const float kk = kb[j], vv = vb[j];
        const int tn = t0 + j + 4;
        if (tn < WKV_L) {
          kb[j] = bf2f(kg[cb + (size_t)tn * A_]);
          vb[j] = bf2f(vg[cb + (size_t)tn * A_]);
        }
        float ww2 = w + pp;
        float q2  = fmaxf(ww2, kk);
        float e1  = __expf(ww2 - q2);
        float e2  = __expf(kk  - q2);
        aa = e1*aa + e2*vv;
        bb = e1*bb + e2;
        pp = q2;
      }
    }
  }
  __shared__ float saa[WKV_C][WKV_G], sbb[WKV_C][WKV_G], spp[WKV_C][WKV_G];
  saa[c][al] = aa; sbb[c][al] = bb; spp[c][al] = pp;
  __syncthreads();

  // ---- combine: thread i (< WKV_G) walks chunks of channel i, leaving prefixes ----
  if (tid < WKV_G) {
    float Aa = 0.f, Bb = 0.f, Pp = -1e38f;
    const float Lw = (float)WKV_L * w;
    for (int cc = 0; cc < WKV_C; ++cc) {
      const float na = saa[cc][tid], nb = sbb[cc][tid], np = spp[cc][tid];
      saa[cc][tid] = Aa; sbb[cc][tid] = Bb; spp[cc][tid] = Pp;   // incoming prefix
      const float p1 = Pp + Lw;
      const float pc = fmaxf(p1, np);
      const float f1 = __expf(p1 - pc);
      const float f2 = __expf(np - pc);
      Aa = f1*Aa + f2*na;
      Bb = f1*Bb + f2*nb;
      Pp = pc;
    }
  }
  __syncthreads();
  aa = saa[c][al]; bb = sbb[c][al]; pp = spp[c][al];

  // ---- pass 2: outputs with true prefix state ----
  {
    float kb[4], vb[4], rb[4];
#pragma unroll
    for (int j = 0; j < 4; ++j) {
      kb[j] = bf2f(kg[cb + (size_t)j * A_]);
      vb[j] = bf2f(vg[cb + (size_t)j * A_]);
      rb[j] = bf2f(rg[cb + (size_t)j * A_]);
    }
    for (int t0 = 0; t0 < WKV_L; t0 += 4) {
#pragma unroll
      for (int j = 0; j < 4; ++j) {
        const float kk = kb[j], vv = vb[j], rr = rb[j];
        const int tn = t0 + j + 4;
        if (tn < WKV_L) {
          kb[j] = bf2f(kg[cb + (size_t)tn * A_]);
          vb[j] = bf2f(vg[cb + (size_t)tn * A_]);
          rb[j] = bf2f(rg[cb + (size_t)tn * A_]);
        }
        float ww = tf + kk;
        float q  = fmaxf(pp, ww);
        float e1 = __expf(pp - q);
        float e2 = __expf(ww - q);
        float o  = (e1*aa + e2*vv) / (e1*bb + e2);
        float sr = 1.f / (1.f + __expf(-rr));
        rwkv[cb + (size_t)(t0 + j) * A_] = f2bf(sr * o);
        float ww2 = w + pp;
        float q2  = fmaxf(ww2, kk);
        e1 = __expf(ww2 - q2);
        e2 = __expf(kk  - q2);
        aa = e1*aa + e2*vv;
        bb = e1*bb + e2;
        pp = q2;
      }
    }
  }
}

// ---------------- bf16 GEMM, m97 structure ----------------
enum { EPI_BF16 = 0, EPI_ADDIP = 1, EPI_RELU2 = 2, EPI_SIGADD = 3 };

template <int EPI>
__global__ __launch_bounds__(256) void gemm_bt_kernel(
    const unsigned short* __restrict__ Ap, const unsigned short* __restrict__ Bp,
    void* __restrict__ Cp, int K, int N,
    const unsigned short* __restrict__ sigb)
{
  __shared__ unsigned short As[128 * 32];
  __shared__ unsigned short Bs[128 * 32];
  const int tid  = threadIdx.x;
  const int lane = tid & 63;
  const int wv   = tid >> 6;
  const int wr   = wv >> 1, wc = wv & 1;
  const long row0 = (long)blockIdx.y * 128;
  const long col0 = (long)blockIdx.x * 128;
  const unsigned short* Ab = Ap + (size_t)row0 * K;
  const unsigned short* Bb = Bp + (size_t)col0 * K;
  const int srow = tid >> 2;          // 0..63
  const int scol = (tid & 3) << 3;    // 0,8,16,24
  const int lr = lane & 15;
  const int hi = lane >> 4;
  f32x4 acc[4][4] = {};
  for (int kt = 0; kt < K; kt += 32) {
    gload_lds16(Ab + (size_t)srow        * K + kt + scol, As + tid * 8);
    gload_lds16(Ab + (size_t)(srow + 64) * K + kt + scol, As + 2048 + tid * 8);
    gload_lds16(Bb + (size_t)srow        * K + kt + scol, Bs + tid * 8);
    gload_lds16(Bb + (size_t)(srow + 64) * K + kt + scol, Bs + 2048 + tid * 8);
    __syncthreads();
    bf16x8 af[4], bfr[4];
#pragma unroll
    for (int m = 0; m < 4; ++m)
      af[m] = __builtin_bit_cast(bf16x8,
          *(const short8*)(As + (wr*64 + m*16 + lr) * 32 + hi * 8));
#pragma unroll
    for (int n = 0; n < 4; ++n)
      bfr[n] = __builtin_bit_cast(bf16x8,
          *(const short8*)(Bs + (wc*64 + n*16 + lr) * 32 + hi * 8));
#pragma unroll
    for (int m = 0; m < 4; ++m)
#pragma unroll
      for (int n = 0; n < 4; ++n)
        acc[m][n] = __builtin_amdgcn_mfma_f32_16x16x32_bf16(af[m], bfr[n], acc[m][n], 0, 0, 0);
    __syncthreads();
  }
  // C/D layout: col = lane&15, row = (lane>>4)*4 + j
#pragma unroll
  for (int m = 0; m < 4; ++m) {
#pragma unroll
    for (int n = 0; n < 4; ++n) {
      const long col = col0 + wc*64 + n*16 + lr;
#pragma unroll
      for (int j = 0; j < 4; ++j) {
        const long row = row0 + wr*64 + m*16 + hi*4 + j;
        const size_t idx = (size_t)row * N + col;
        const float v = acc[m][n][j];
        if (EPI == EPI_BF16) {
          ((unsigned short*)Cp)[idx] = f2bf(v);
        } else if (EPI == EPI_ADDIP) {
          float* C = (float*)Cp;
          C[idx] = C[idx] + v;                       // in-place residual add
        } else if (EPI == EPI_RELU2) {
          float rr = v > 0.f ? v : 0.f;
          ((unsigned short*)Cp)[idx] = f2bf(rr * rr);
        } else {                                     // EPI_SIGADD
          float s = 1.f / (1.f + __expf(-bf2f(sigb[idx])));
          float* C = (float*)Cp;
          C[idx] = C[idx] + s * v;
        }
      }
    }
  }
}

// ---------------- workspace layout ----------------
#define MB(x) ((size_t)(x) << 20)
#define WS_NEED MB(184)

extern "C" void kernel_launch(void* const* d_in, const int* in_sizes, int n_in,
                              void* d_out, int out_size, void* d_ws, size_t ws_size,
                              hipStream_t stream) {
  const float* hidden     = (const float*)d_in[0];
  const float* pre_w      = (const float*)d_in[1];
  const float* pre_b      = (const float*)d_in[2];
  const float* ln1_w      = (const float*)d_in[3];
  const float* ln1_b      = (const float*)d_in[4];
  const float* ln2_w      = (const float*)d_in[5];
  const float* ln2_b      = (const float*)d_in[6];
  const float* time_decay = (const float*)d_in[7];
  const float* time_first = (const float*)d_in[8];
  const float* tmk        = (const float*)d_in[9];
  const float* tmv        = (const float*)d_in[10];
  const float* tmr        = (const float*)d_in[11];
  const float* Wk         = (const float*)d_in[12];
  const float* Wv         = (const float*)d_in[13];
  const float* Wr         = (const float*)d_in[14];
  const float* Wo         = (const float*)d_in[15];
  const float* f_tmk      = (const float*)d_in[16];
  const float* f_tmr      = (const float*)d_in[17];
  const float* f_Wk       = (const float*)d_in[18];
  const float* f_Wr       = (const float*)d_in[19];
  const float* f_Wv       = (const float*)d_in[20];
  float* out = (float*)d_out;
  char*  ws  = (char*)d_ws;

  if (ws_size < WS_NEED) {               // diagnostic canary: absmax ~1000 => ws too small
    canary_kernel<<<1, 256, 0, stream>>>(out);
    return;
  }

  unsigned short* WkT  = (unsigned short*)(ws + MB(0));
  unsigned short* WvT  = (unsigned short*)(ws + MB(8));
  unsigned short* WrT  = (unsigned short*)(ws + MB(16));
  unsigned short* WoT  = (unsigned short*)(ws + MB(24));
  unsigned short* fWrT = (unsigned short*)(ws + MB(32));
  unsigned short* fWkT = (unsigned short*)(ws + MB(40));
  unsigned short* fWvT = (unsigned short*)(ws + MB(72));
  unsigned short* S1   = (unsigned short*)(ws + MB(104));  // x1 -> rwkv
  unsigned short* KK   = (unsigned short*)(ws + MB(104));  // kk2 strip (aliases S1+S4)
  unsigned short* S4   = (unsigned short*)(ws + MB(120));  // r
  unsigned short* S2   = (unsigned short*)(ws + MB(136));  // k -> x2
  unsigned short* S3   = (unsigned short*)(ws + MB(152));  // v -> r2pre
  unsigned short* M1   = (unsigned short*)(ws + MB(168));  // mix scratch

  const dim3 blk(256);

  // 1) weight transpose+convert
  transpose_bf16_kernel<<<dim3(64, 64),  blk, 0, stream>>>(Wk,   WkT,  2048, 2048);
  transpose_bf16_kernel<<<dim3(64, 64),  blk, 0, stream>>>(Wv,   WvT,  2048, 2048);
  transpose_bf16_kernel<<<dim3(64, 64),  blk, 0, stream>>>(Wr,   WrT,  2048, 2048);
  transpose_bf16_kernel<<<dim3(64, 64),  blk, 0, stream>>>(Wo,   WoT,  2048, 2048);
  transpose_bf16_kernel<<<dim3(64, 64),  blk, 0, stream>>>(f_Wr, fWrT, 2048, 2048);
  transpose_bf16_kernel<<<dim3(256, 64), blk, 0, stream>>>(f_Wk, fWkT, 2048, 8192);
  transpose_bf16_kernel<<<dim3(64, 256), blk, 0, stream>>>(f_Wv, fWvT, 8192, 2048);

  // 2) pre-LN + LN1: h0 -> d_out (fp32), x1 -> S1 (bf16)
  ln_pre_kernel<<<BT_, blk, 0, stream>>>(hidden, pre_w, pre_b, ln1_w, ln1_b, out, S1);

  // 3) k/v/r projections via shared mix buffer M1
  mix1_kernel<<<BT_, blk, 0, stream>>>(S1, tmk, M1);
  gemm_bt_kernel<EPI_BF16><<<dim3(16, 32), blk, 0, stream>>>(M1, WkT, S2, 2048, 2048, nullptr);
  mix1_kernel<<<BT_, blk, 0, stream>>>(S1, tmv, M1);
  gemm_bt_kernel<EPI_BF16><<<dim3(16, 32), blk, 0, stream>>>(M1, WvT, S3, 2048, 2048, nullptr);
  mix1_kernel<<<BT_, blk, 0, stream>>>(S1, tmr, M1);
  gemm_bt_kernel<EPI_BF16><<<dim3(16, 32), blk, 0, stream>>>(M1, WrT, S4, 2048, 2048, nullptr);

  // 4) chunk-parallel WKV scan + sigmoid(r)*wkv -> S1 (x1 dead)
  wkv_scan_kernel<<<dim3(128), dim3(1024), 0, stream>>>(S2, S3, S4, time_first, time_decay, S1);

  // 5) h1 = h0 + rwkv @ Wo  (in-place on d_out)
  gemm_bt_kernel<EPI_ADDIP><<<dim3(16, 32), blk, 0, stream>>>(S1, WoT, out, 2048, 2048, nullptr);

  // 6) LN2: d_out -> x2 (S2, k dead)
  ln_single_kernel<<<BT_, blk, 0, stream>>>(out, ln2_w, ln2_b, S2);

  // 7) r2pre = rx2 @ f_Wr -> S3 (v dead)
  mix1_kernel<<<BT_, blk, 0, stream>>>(S2, f_tmr, M1);
  gemm_bt_kernel<EPI_BF16><<<dim3(16, 32), blk, 0, stream>>>(M1, fWrT, S3, 2048, 2048, nullptr);

  // 8) kx2 -> M1 (stays live for both strips)
  mix1_kernel<<<BT_, blk, 0, stream>>>(S2, f_tmk, M1);

  // 9) FF in 2 strips of 2048 rows
  for (int s = 0; s < 2; ++s) {
    const size_t rowoff = (size_t)s * 2048;
    gemm_bt_kernel<EPI_RELU2><<<dim3(64, 16), blk, 0, stream>>>(
        M1 + rowoff * 2048, fWkT, KK, 2048, 8192, nullptr);
    gemm_bt_kernel<EPI_SIGADD><<<dim3(16, 16), blk, 0, stream>>>(
        KK, fWvT, out + rowoff * 2048, 8192, 2048, S3 + rowoff * 2048);
  }
}

// Round 4
// 861.700 us; speedup vs baseline: 2.3164x; 1.2744x over previous
//
#include <hip/hip_runtime.h>

// ---------------- problem constants ----------------
#define B_  2
#define T_  2048
#define H_  2048
#define A_  2048
#define F_  8192
#define BT_ 4096   // B*T rows

typedef __bf16  bf16x8 __attribute__((ext_vector_type(8)));
typedef float   f32x4  __attribute__((ext_vector_type(4)));
typedef short   short8 __attribute__((ext_vector_type(8)));

__device__ __forceinline__ float bf2f(unsigned short b) {
  return __uint_as_float(((unsigned)b) << 16);
}
__device__ __forceinline__ unsigned short f2bf(float f) {
  unsigned u = __float_as_uint(f);
  unsigned r = (u + 0x7FFFu + ((u >> 16) & 1u)) >> 16;   // RNE
  return (unsigned short)r;
}

// global -> LDS direct copy, 16B per lane
typedef __attribute__((address_space(3))) void lds_void_t;
typedef __attribute__((address_space(1))) const void gc_void_t;
__device__ __forceinline__ void gload_lds16(const void* g, void* l) {
  __builtin_amdgcn_global_load_lds((gc_void_t*)g, (lds_void_t*)l, 16, 0, 0);
}

// ---------------- canary: ws too small diagnostic ----------------
__global__ void canary_kernel(float* out) { out[threadIdx.x] = 1000.0f; }

// ---------------- weight transpose + fp32->bf16 ----------------
__global__ __launch_bounds__(256) void transpose_bf16_kernel(
    const float* __restrict__ src, unsigned short* __restrict__ dst, int Kd, int Nd)
{
  __shared__ float tile[32][33];
  const int tx = threadIdx.x & 31;
  const int ty = threadIdx.x >> 5;         // 0..7
  const int n0 = blockIdx.x * 32;
  const int k0 = blockIdx.y * 32;
#pragma unroll
  for (int i = 0; i < 32; i += 8)
    tile[ty + i][tx] = src[(size_t)(k0 + ty + i) * Nd + n0 + tx];
  __syncthreads();
#pragma unroll
  for (int i = 0; i < 32; i += 8)
    dst[(size_t)(n0 + ty + i) * Kd + k0 + tx] = f2bf(tile[tx][ty + i]);
}

// ---------------- block reduction (sum, sumsq) ----------------
__device__ __forceinline__ void block_reduce2(float& a, float& b) {
#pragma unroll
  for (int off = 32; off > 0; off >>= 1) {
    a += __shfl_down(a, off, 64);
    b += __shfl_down(b, off, 64);
  }
  __shared__ float sa[4], sb[4];
  const int lane = threadIdx.x & 63, w = threadIdx.x >> 6;
  __syncthreads();
  if (lane == 0) { sa[w] = a; sb[w] = b; }
  __syncthreads();
  a = sa[0] + sa[1] + sa[2] + sa[3];
  b = sb[0] + sb[1] + sb[2] + sb[3];
}

// ---------------- pre-LN + LN1 fused ----------------
__global__ __launch_bounds__(256) void ln_pre_kernel(
    const float* __restrict__ hidden,
    const float* __restrict__ pw, const float* __restrict__ pb,
    const float* __restrict__ w1, const float* __restrict__ b1,
    float* __restrict__ h0, unsigned short* __restrict__ x1)
{
  const int row = blockIdx.x, tid = threadIdx.x;
  const int c0 = tid * 8;
  const size_t base = (size_t)row * H_ + c0;
  float x[8];
  float4 v0 = *(const float4*)(hidden + base);
  float4 v1 = *(const float4*)(hidden + base + 4);
  x[0]=v0.x; x[1]=v0.y; x[2]=v0.z; x[3]=v0.w;
  x[4]=v1.x; x[5]=v1.y; x[6]=v1.z; x[7]=v1.w;
  float s = 0.f, s2 = 0.f;
#pragma unroll
  for (int j = 0; j < 8; ++j) { s += x[j]; s2 += x[j]*x[j]; }
  block_reduce2(s, s2);
  float mu  = s * (1.f / H_);
  float inv = rsqrtf(fmaxf(s2 * (1.f / H_) - mu*mu, 0.f) + 1e-5f);
  float y[8];
#pragma unroll
  for (int j = 0; j < 8; ++j) y[j] = (x[j] - mu) * inv * pw[c0+j] + pb[c0+j];
  *(float4*)(h0 + base)     = make_float4(y[0],y[1],y[2],y[3]);
  *(float4*)(h0 + base + 4) = make_float4(y[4],y[5],y[6],y[7]);
  s = 0.f; s2 = 0.f;
#pragma unroll
  for (int j = 0; j < 8; ++j) { s += y[j]; s2 += y[j]*y[j]; }
  block_reduce2(s, s2);
  mu  = s * (1.f / H_);
  inv = rsqrtf(fmaxf(s2 * (1.f / H_) - mu*mu, 0.f) + 1e-5f);
  unsigned o[4];
#pragma unroll
  for (int p = 0; p < 4; ++p) {
    unsigned lo = f2bf((y[2*p]   - mu) * inv * w1[c0+2*p]   + b1[c0+2*p]);
    unsigned hi = f2bf((y[2*p+1] - mu) * inv * w1[c0+2*p+1] + b1[c0+2*p+1]);
    o[p] = lo | (hi << 16);
  }
  *(uint4*)(x1 + base) = make_uint4(o[0], o[1], o[2], o[3]);
}

// ---------------- single LN (fp32 in) -> bf16 ----------------
__global__ __launch_bounds__(256) void ln_single_kernel(
    const float* __restrict__ in, const float* __restrict__ w_, const float* __restrict__ b_,
    unsigned short* __restrict__ outb)
{
  const int row = blockIdx.x, tid = threadIdx.x;
  const int c0 = tid * 8;
  const size_t base = (size_t)row * H_ + c0;
  float x[8];
  float4 v0 = *(const float4*)(in + base);
  float4 v1 = *(const float4*)(in + base + 4);
  x[0]=v0.x; x[1]=v0.y; x[2]=v0.z; x[3]=v0.w;
  x[4]=v1.x; x[5]=v1.y; x[6]=v1.z; x[7]=v1.w;
  float s = 0.f, s2 = 0.f;
#pragma unroll
  for (int j = 0; j < 8; ++j) { s += x[j]; s2 += x[j]*x[j]; }
  block_reduce2(s, s2);
  float mu  = s * (1.f / H_);
  float inv = rsqrtf(fmaxf(s2 * (1.f / H_) - mu*mu, 0.f) + 1e-5f);
  unsigned o[4];
#pragma unroll
  for (int p = 0; p < 4; ++p) {
    unsigned lo = f2bf((x[2*p]   - mu) * inv * w_[c0+2*p]   + b_[c0+2*p]);
    unsigned hi = f2bf((x[2*p+1] - mu) * inv * w_[c0+2*p+1] + b_[c0+2*p+1]);
    o[p] = lo | (hi << 16);
  }
  *(uint4*)(outb + base) = make_uint4(o[0], o[1], o[2], o[3]);
}

// ---------------- token-shift + mix (single output) ----------------
__global__ __launch_bounds__(256) void mix1_kernel(
    const unsigned short* __restrict__ x,
    const float* __restrict__ tm_,
    unsigned short* __restrict__ outb)
{
  const int row = blockIdx.x;
  const int t = row & (T_ - 1);
  const int c0 = threadIdx.x * 8;
  const size_t base = (size_t)row * H_ + c0;
  uint4 xv = *(const uint4*)(x + base);
  uint4 cv = make_uint4(0u,0u,0u,0u);
  if (t > 0) cv = *(const uint4*)(x + base - H_);
  const unsigned xs[4] = {xv.x, xv.y, xv.z, xv.w};
  const unsigned cs[4] = {cv.x, cv.y, cv.z, cv.w};
  unsigned oo[4];
#pragma unroll
  for (int p = 0; p < 4; ++p) {
    unsigned w = 0;
#pragma unroll
    for (int h = 0; h < 2; ++h) {
      const int j = p*2 + h;
      float xf = bf2f((unsigned short)((xs[p] >> (h*16)) & 0xFFFFu));
      float cf = bf2f((unsigned short)((cs[p] >> (h*16)) & 0xFFFFu));
      w |= (unsigned)f2bf(fmaf(xf - cf, tm_[c0+j], cf)) << (h*16);
    }
    oo[p] = w;
  }
  *(uint4*)(outb + base) = make_uint4(oo[0],oo[1],oo[2],oo[3]);
}

// ---------------- chunked-parallel WKV scan ----------------
#define WKV_G 32   // channels per block
#define WKV_C 32   // chunks over T
#define WKV_L 64   // steps per chunk (WKV_C*WKV_L == T_)

__global__ __launch_bounds__(1024) void wkv_scan_kernel(
    const unsigned short* __restrict__ kg, const unsigned short* __restrict__ vg,
    const unsigned short* __restrict__ rg,
    const float* __restrict__ time_first, const float* __restrict__ time_decay,
    unsigned short* __restrict__ rwkv)
{
  const int tid = threadIdx.x;
  const int al  = tid & (WKV_G - 1);        // channel within group
  const int c   = tid >> 5;                 // chunk index 0..31
  const int b   = blockIdx.x >> 6;          // 64 groups per batch
  const int ag  = blockIdx.x & 63;
  const int a   = ag * WKV_G + al;
  const float tf = time_first[a];
  const float w  = -__expf(time_decay[a]);
  const size_t cb = (size_t)b * T_ * A_ + a + (size_t)c * WKV_L * A_;

  // ---- pass 1: per-chunk summary from zero state (k,v only) ----
  float aa = 0.f, bb = 0.f, pp = -1e38f;
  {
    float kb[4], vb[4];
#pragma unroll
    for (int j = 0; j < 4; ++j) {
      kb[j] = bf2f(kg[cb + (size_t)j * A_]);
      vb[j] = bf2f(vg[cb + (size_t)j * A_]);
    }
    for (int t0 = 0; t0 < WKV_L; t0 += 4) {
#pragma unroll
      for (int j = 0; j < 4; ++j) {
        const float kk = kb[j], vv = vb[j];
        const int tn = t0 + j + 4;
        if (tn < WKV_L) {
          kb[j] = bf2f(kg[cb + (size_t)tn * A_]);
          vb[j] = bf2f(vg[cb + (size_t)tn * A_]);
        }
        float ww2 = w + pp;
        float q2  = fmaxf(ww2, kk);
        float e1  = __expf(ww2 - q2);
        float e2  = __expf(kk  - q2);
        aa = e1*aa + e2*vv;
        bb = e1*bb + e2;
        pp = q2;
      }
    }
  }
  __shared__ float saa[WKV_C][WKV_G], sbb[WKV_C][WKV_G], spp[WKV_C][WKV_G];
  saa[c][al] = aa; sbb[c][al] = bb; spp[c][al] = pp;
  __syncthreads();

  // ---- combine: thread i (< WKV_G) walks chunks of channel i ----
  if (tid < WKV_G) {
    float Aa = 0.f, Bb = 0.f, Pp = -1e38f;
    const float Lw = (float)WKV_L * w;
    for (int cc = 0; cc < WKV_C; ++cc) {
      const float na = saa[cc][tid], nb = sbb[cc][tid], np = spp[cc][tid];
      saa[cc][tid] = Aa; sbb[cc][tid] = Bb; spp[cc][tid] = Pp;   // incoming prefix
      const float p1 = Pp + Lw;
      const float pc = fmaxf(p1, np);
      const float f1 = __expf(p1 - pc);
      const float f2 = __expf(np - pc);
      Aa = f1*Aa + f2*na;
      Bb = f1*Bb + f2*nb;
      Pp = pc;
    }
  }
  __syncthreads();
  aa = saa[c][al]; bb = sbb[c][al]; pp = spp[c][al];

  // ---- pass 2: outputs with true prefix state ----
  {
    float kb[4], vb[4], rb[4];
#pragma unroll
    for (int j = 0; j < 4; ++j) {
      kb[j] = bf2f(kg[cb + (size_t)j * A_]);
      vb[j] = bf2f(vg[cb + (size_t)j * A_]);
      rb[j] = bf2f(rg[cb + (size_t)j * A_]);
    }
    for (int t0 = 0; t0 < WKV_L; t0 += 4) {
#pragma unroll
      for (int j = 0; j < 4; ++j) {
        const float kk = kb[j], vv = vb[j], rr = rb[j];
        const int tn = t0 + j + 4;
        if (tn < WKV_L) {
          kb[j] = bf2f(kg[cb + (size_t)tn * A_]);
          vb[j] = bf2f(vg[cb + (size_t)tn * A_]);
          rb[j] = bf2f(rg[cb + (size_t)tn * A_]);
        }
        float ww = tf + kk;
        float q  = fmaxf(pp, ww);
        float e1 = __expf(pp - q);
        float e2 = __expf(ww - q);
        float o  = (e1*aa + e2*vv) / (e1*bb + e2);
        float sr = 1.f / (1.f + __expf(-rr));
        rwkv[cb + (size_t)(t0 + j) * A_] = f2bf(sr * o);
        float ww2 = w + pp;
        float q2  = fmaxf(ww2, kk);
        e1 = __expf(ww2 - q2);
        e2 = __expf(kk  - q2);
        aa = e1*aa + e2*vv;
        bb = e1*bb + e2;
        pp = q2;
      }
    }
  }
}

// ---------------- bf16 GEMM, depth-2 prefetch pipeline (T3/T4-lite) ----------------
// A [M,K] bf16 rm, Bt [N,K] bf16 rm. Tile 128x128, BK=32, 3 LDS buffers.
// Pipeline: stage t+2 in flight; s_waitcnt vmcnt(4) waits tile t only (t+1 stays
// in flight across the barrier -- never drain to 0 in the main loop).
enum { EPI_BF16 = 0, EPI_ADDIP = 1, EPI_RELU2 = 2, EPI_SIGADD = 3 };

template <int EPI>
__global__ __launch_bounds__(256) void gemm_bt_kernel(
    const unsigned short* __restrict__ Ap, const unsigned short* __restrict__ Bp,
    void* __restrict__ Cp, int K, int N,
    const unsigned short* __restrict__ sigb)
{
  __shared__ unsigned short As[3 * 128 * 32];
  __shared__ unsigned short Bs[3 * 128 * 32];
  const int tid  = threadIdx.x;
  const int lane = tid & 63;
  const int wv   = tid >> 6;
  const int wr   = wv >> 1, wc = wv & 1;
  const long row0 = (long)blockIdx.y * 128;
  const long col0 = (long)blockIdx.x * 128;
  const unsigned short* Ab = Ap + (size_t)row0 * K;
  const unsigned short* Bb = Bp + (size_t)col0 * K;
  const int srow = tid >> 2;          // 0..63
  const int scol = (tid & 3) << 3;    // 0,8,16,24
  const int lr = lane & 15;
  const int hi = lane >> 4;
  f32x4 acc[4][4] = {};

#define STAGE(bufi, tt) do {                                                   \
    unsigned short* asb = As + (bufi) * 4096;                                  \
    unsigned short* bsb = Bs + (bufi) * 4096;                                  \
    const size_t ko = (size_t)(tt) * 32 + scol;                                \
    gload_lds16(Ab + (size_t)srow        * K + ko, asb + tid * 8);             \
    gload_lds16(Ab + (size_t)(srow + 64) * K + ko, asb + 2048 + tid * 8);      \
    gload_lds16(Bb + (size_t)srow        * K + ko, bsb + tid * 8);             \
    gload_lds16(Bb + (size_t)(srow + 64) * K + ko, bsb + 2048 + tid * 8);      \
  } while (0)

  const int nt = K >> 5;
  STAGE(0, 0);
  STAGE(1, 1);
  int cur = 0;
  for (int t = 0; t < nt; ++t) {
    if (t + 1 < nt) {
      asm volatile("s_waitcnt vmcnt(4)" ::: "memory");   // tile t done; t+1 in flight
    } else {
      asm volatile("s_waitcnt vmcnt(0)" ::: "memory");   // last tile: drain
    }
    __builtin_amdgcn_s_barrier();
    if (t + 2 < nt) {
      int nb = cur + 2; if (nb >= 3) nb -= 3;
      STAGE(nb, t + 2);
    }
    const unsigned short* asb = As + cur * 4096;
    const unsigned short* bsb = Bs + cur * 4096;
    bf16x8 af[4], bfr[4];
#pragma unroll
    for (int m = 0; m < 4; ++m)
      af[m] = __builtin_bit_cast(bf16x8,
          *(const short8*)(asb + (wr*64 + m*16 + lr) * 32 + hi * 8));
#pragma unroll
    for (int n = 0; n < 4; ++n)
      bfr[n] = __builtin_bit_cast(bf16x8,
          *(const short8*)(bsb + (wc*64 + n*16 + lr) * 32 + hi * 8));
#pragma unroll
    for (int m = 0; m < 4; ++m)
#pragma unroll
      for (int n = 0; n < 4; ++n)
        acc[m][n] = __builtin_amdgcn_mfma_f32_16x16x32_bf16(af[m], bfr[n], acc[m][n], 0, 0, 0);
    cur = (cur + 1 == 3) ? 0 : cur + 1;
  }
#undef STAGE

  // C/D layout: col = lane&15, row = (lane>>4)*4 + j
#pragma unroll
  for (int m = 0; m < 4; ++m) {
#pragma unroll
    for (int n = 0; n < 4; ++n) {
      const long col = col0 + wc*64 + n*16 + lr;
#pragma unroll
      for (int j = 0; j < 4; ++j) {
        const long row = row0 + wr*64 + m*16 + hi*4 + j;
        const size_t idx = (size_t)row * N + col;
        const float v = acc[m][n][j];
        if (EPI == EPI_BF16) {
          ((unsigned short*)Cp)[idx] = f2bf(v);
        } else if (EPI == EPI_ADDIP) {
          float* C = (float*)Cp;
          C[idx] = C[idx] + v;                       // in-place residual add
        } else if (EPI == EPI_RELU2) {
          float rr = v > 0.f ? v : 0.f;
          ((unsigned short*)Cp)[idx] = f2bf(rr * rr);
        } else {                                     // EPI_SIGADD
          float s = 1.f / (1.f + __expf(-bf2f(sigb[idx])));
          float* C = (float*)Cp;
          C[idx] = C[idx] + s * v;
        }
      }
    }
  }
}

// ---------------- workspace layout ----------------
// 0..32   fWkT [8192,2048] bf16     32..64  fWvT [2048,8192] bf16
// 64..72  WkT   72..80 WvT   80..88 WrT   88..96 WoT   96..104 fWrT
// 104..120 S1 (x1 -> rwkv)   120..136 S4 (r)
// 136..152 S2 (k -> x2)      152..168 S3 (v -> r2pre)   168..184 M1 (mix)
// KK (kk2 [4096,8192] bf16, 64MB) aliases 64..128 (small weights + S1 + S4 head),
// all dead by the FF GEMMs.
#define MB(x) ((size_t)(x) << 20)
#define WS_NEED MB(184)

extern "C" void kernel_launch(void* const* d_in, const int* in_sizes, int n_in,
                              void* d_out, int out_size, void* d_ws, size_t ws_size,
                              hipStream_t stream) {
  const float* hidden     = (const float*)d_in[0];
  const float* pre_w      = (const float*)d_in[1];
  const float* pre_b      = (const float*)d_in[2];
  const float* ln1_w      = (const float*)d_in[3];
  const float* ln1_b      = (const float*)d_in[4];
  const float* ln2_w      = (const float*)d_in[5];
  const float* ln2_b      = (const float*)d_in[6];
  const float* time_decay = (const float*)d_in[7];
  const float* time_first = (const float*)d_in[8];
  const float* tmk        = (const float*)d_in[9];
  const float* tmv        = (const float*)d_in[10];
  const float* tmr        = (const float*)d_in[11];
  const float* Wk         = (const float*)d_in[12];
  const float* Wv         = (const float*)d_in[13];
  const float* Wr         = (const float*)d_in[14];
  const float* Wo         = (const float*)d_in[15];
  const float* f_tmk      = (const float*)d_in[16];
  const float* f_tmr      = (const float*)d_in[17];
  const float* f_Wk       = (const float*)d_in[18];
  const float* f_Wr       = (const float*)d_in[19];
  const float* f_Wv       = (const float*)d_in[20];
  float* out = (float*)d_out;
  char*  ws  = (char*)d_ws;

  if (ws_size < WS_NEED) {               // diagnostic canary: absmax ~1000 => ws too small
    canary_kernel<<<1, 256, 0, stream>>>(out);
    return;
  }

  unsigned short* fWkT = (unsigned short*)(ws + MB(0));
  unsigned short* fWvT = (unsigned short*)(ws + MB(32));
  unsigned short* WkT  = (unsigned short*)(ws + MB(64));
  unsigned short* WvT  = (unsigned short*)(ws + MB(72));
  unsigned short* WrT  = (unsigned short*)(ws + MB(80));
  unsigned short* WoT  = (unsigned short*)(ws + MB(88));
  unsigned short* fWrT = (unsigned short*)(ws + MB(96));
  unsigned short* KK   = (unsigned short*)(ws + MB(64));   // kk2 full, aliases dead data
  unsigned short* S1   = (unsigned short*)(ws + MB(104));  // x1 -> rwkv
  unsigned short* S4   = (unsigned short*)(ws + MB(120));  // r
  unsigned short* S2   = (unsigned short*)(ws + MB(136));  // k -> x2
  unsigned short* S3   = (unsigned short*)(ws + MB(152));  // v -> r2pre
  unsigned short* M1   = (unsigned short*)(ws + MB(168));  // mix scratch -> kx2

  const dim3 blk(256);

  // 1) weight transpose+convert: src [Kd,Nd] fp32 -> dst [Nd,Kd] bf16
  transpose_bf16_kernel<<<dim3(64, 64),  blk, 0, stream>>>(Wk,   WkT,  2048, 2048);
  transpose_bf16_kernel<<<dim3(64, 64),  blk, 0, stream>>>(Wv,   WvT,  2048, 2048);
  transpose_bf16_kernel<<<dim3(64, 64),  blk, 0, stream>>>(Wr,   WrT,  2048, 2048);
  transpose_bf16_kernel<<<dim3(64, 64),  blk, 0, stream>>>(Wo,   WoT,  2048, 2048);
  transpose_bf16_kernel<<<dim3(64, 64),  blk, 0, stream>>>(f_Wr, fWrT, 2048, 2048);
  transpose_bf16_kernel<<<dim3(256, 64), blk, 0, stream>>>(f_Wk, fWkT, 2048, 8192);
  transpose_bf16_kernel<<<dim3(64, 256), blk, 0, stream>>>(f_Wv, fWvT, 8192, 2048);

  // 2) pre-LN + LN1: h0 -> d_out (fp32), x1 -> S1 (bf16)
  ln_pre_kernel<<<BT_, blk, 0, stream>>>(hidden, pre_w, pre_b, ln1_w, ln1_b, out, S1);

  // 3) k/v/r projections via shared mix buffer M1
  mix1_kernel<<<BT_, blk, 0, stream>>>(S1, tmk, M1);
  gemm_bt_kernel<EPI_BF16><<<dim3(16, 32), blk, 0, stream>>>(M1, WkT, S2, 2048, 2048, nullptr);
  mix1_kernel<<<BT_, blk, 0, stream>>>(S1, tmv, M1);
  gemm_bt_kernel<EPI_BF16><<<dim3(16, 32), blk, 0, stream>>>(M1, WvT, S3, 2048, 2048, nullptr);
  mix1_kernel<<<BT_, blk, 0, stream>>>(S1, tmr, M1);
  gemm_bt_kernel<EPI_BF16><<<dim3(16, 32), blk, 0, stream>>>(M1, WrT, S4, 2048, 2048, nullptr);

  // 4) chunk-parallel WKV scan + sigmoid(r)*wkv -> S1 (x1 dead)
  wkv_scan_kernel<<<dim3(128), dim3(1024), 0, stream>>>(S2, S3, S4, time_first, time_decay, S1);

  // 5) h1 = h0 + rwkv @ Wo  (in-place on d_out)
  gemm_bt_kernel<EPI_ADDIP><<<dim3(16, 32), blk, 0, stream>>>(S1, WoT, out, 2048, 2048, nullptr);

  // 6) LN2: d_out -> x2 (S2, k dead)
  ln_single_kernel<<<BT_, blk, 0, stream>>>(out, ln2_w, ln2_b, S2);

  // 7) r2pre = rx2 @ f_Wr -> S3 (v dead)
  mix1_kernel<<<BT_, blk, 0, stream>>>(S2, f_tmr, M1);
  gemm_bt_kernel<EPI_BF16><<<dim3(16, 32), blk, 0, stream>>>(M1, fWrT, S3, 2048, 2048, nullptr);

  // 8) kx2 -> M1
  mix1_kernel<<<BT_, blk, 0, stream>>>(S2, f_tmk, M1);

  // 9) FF full-M: kk2 = relu(kx2@f_Wk)^2 -> KK (64MB, aliases dead buffers);
  //    out += sigmoid(r2pre) * (kk2 @ f_Wv)
  gemm_bt_kernel<EPI_RELU2><<<dim3(64, 32), blk, 0, stream>>>(M1, fWkT, KK, 2048, 8192, nullptr);
  gemm_bt_kernel<EPI_SIGADD><<<dim3(16, 32), blk, 0, stream>>>(KK, fWvT, out, 8192, 2048, S3);
}